// Round 5
// baseline (163.784 us; speedup 1.0000x reference)
//
#include <hip/hip_runtime.h>
#include <hip/hip_bf16.h>
#include <stdint.h>

#define S_LEN 2048
#define D_DIM 1024
#define P_DIM 256
#define NQ_   8192
#define M_TOT 16384  // B*S

#define BM 32
#define BN 256
#define BK 64

typedef __attribute__((ext_vector_type(4))) float  f32x4;
typedef __attribute__((ext_vector_type(8))) __bf16 bf16x8;
typedef __attribute__((ext_vector_type(4))) __bf16 bf16x4;

__device__ __forceinline__ void async16(const void* g, void* l) {
    __builtin_amdgcn_global_load_lds(
        (const __attribute__((address_space(1))) uint32_t*)g,
        (__attribute__((address_space(3))) uint32_t*)l, 16, 0, 0);
}

__device__ __forceinline__ void nts(f32x4 v, float* p) {
    __builtin_nontemporal_store(v, (f32x4*)p);
}

// ---------------- Kernel 0: W [1024][256] f32 -> WT [256][1024] bf16 ----------
__global__ __launch_bounds__(1024) void wt_kernel(const float* __restrict__ W,
                                                  __bf16* __restrict__ WT) {
    __shared__ __bf16 tile[32][33];
    const int k0 = blockIdx.x * 32;
    const int n0 = blockIdx.y * 32;
    const int tx = threadIdx.x, ty = threadIdx.y;
    tile[ty][tx] = (__bf16)W[(k0 + ty) * P_DIM + (n0 + tx)];
    __syncthreads();
    WT[(n0 + ty) * D_DIM + (k0 + tx)] = tile[tx][ty];
}

// ---------------- Kernel 1: H(bf16) = A @ W + b  ------------------------------
// BM=32,BN=256,BK=64; 256 thr = 4 waves; wave w -> cols [w*64,+64).
// B: async global_load_lds double-buffer (64 KB LDS -> 2 blocks/CU).
// A: per-lane global->VGPR, one-step lookahead, two static register sets
//    (loop unrolled x2 so set index is compile-time -> no scratch).
// __syncthreads() anchors keep prefetches hoisted above compute.
__global__ __launch_bounds__(256, 2) void gemm_kernel(const float*  __restrict__ A,
                                                      const __bf16* __restrict__ WT,
                                                      const float*  __restrict__ bias,
                                                      __bf16*       __restrict__ H) {
    __shared__ __bf16 Bs[2][BN * BK];   // 32 KB x2

    const int tid = threadIdx.x;
    const int w   = tid >> 6;
    const int l   = tid & 63;
    const int lm  = l & 15;
    const int q   = l >> 4;

    const int m0 = blockIdx.x * BM;

    // ---- B async staging (verified R4 geometry): inst j covers rows r*8..+8,
    // r = w*8+j; lane -> row r*8+(l>>3), slot l&7, chunk (l&7)^((l>>3)&7).
    const int brow_l = l >> 3;
    const int bc     = (l & 7) ^ (brow_l & 7);

    auto stageB = [&](int buf, int k0) {
        #pragma unroll
        for (int j = 0; j < 8; ++j) {
            const int r   = w * 8 + j;
            const int row = r * 8 + brow_l;
            async16(WT + (size_t)row * D_DIM + k0 + bc * 8, &Bs[buf][r * 512]);
        }
    };

    // ---- A fragment pointers: lane needs rows m0 + mi*16 + lm, k = kh*32 + q*8
    const float* ap0 = A + (size_t)(m0 + lm)      * D_DIM + q * 8;
    const float* ap1 = A + (size_t)(m0 + 16 + lm) * D_DIM + q * 8;

    f32x4 acc[2][4] = {};
    float4 ra0[2][2][2];  // set0: [mi][kh][half]
    float4 ra1[2][2][2];  // set1

    auto loadA = [&](float4 (&ra)[2][2][2], int k0) {
        #pragma unroll
        for (int kh = 0; kh < 2; ++kh) {
            ra[0][kh][0] = *(const float4*)(ap0 + k0 + kh * 32);
            ra[0][kh][1] = *(const float4*)(ap0 + k0 + kh * 32 + 4);
            ra[1][kh][0] = *(const float4*)(ap1 + k0 + kh * 32);
            ra[1][kh][1] = *(const float4*)(ap1 + k0 + kh * 32 + 4);
        }
    };

    auto compute = [&](const float4 (&ra)[2][2][2], int buf) {
        #pragma unroll
        for (int kh = 0; kh < 2; ++kh) {
            const int pos = ((kh * 4 + q) ^ (lm & 7)) * 8;  // matches staging swizzle
            bf16x8 bfr[4];
            #pragma unroll
            for (int ni = 0; ni < 4; ++ni)
                bfr[ni] = *(const bf16x8*)(&Bs[buf][(w * 64 + ni * 16 + lm) * BK + pos]);
            bf16x8 af[2];
            #pragma unroll
            for (int mi = 0; mi < 2; ++mi) {
                af[mi][0] = (__bf16)ra[mi][kh][0].x; af[mi][1] = (__bf16)ra[mi][kh][0].y;
                af[mi][2] = (__bf16)ra[mi][kh][0].z; af[mi][3] = (__bf16)ra[mi][kh][0].w;
                af[mi][4] = (__bf16)ra[mi][kh][1].x; af[mi][5] = (__bf16)ra[mi][kh][1].y;
                af[mi][6] = (__bf16)ra[mi][kh][1].z; af[mi][7] = (__bf16)ra[mi][kh][1].w;
            }
            #pragma unroll
            for (int mi = 0; mi < 2; ++mi)
                #pragma unroll
                for (int ni = 0; ni < 4; ++ni)
                    acc[mi][ni] = __builtin_amdgcn_mfma_f32_16x16x32_bf16(
                        af[mi], bfr[ni], acc[mi][ni], 0, 0, 0);
        }
    };

    // ---- pipeline: 16 K-steps; step p uses buf/set p&1.
    loadA(ra0, 0);
    stageB(0, 0);
    __syncthreads();

    #pragma unroll 1
    for (int ph = 0; ph < 7; ++ph) {
        const int k1 = (2 * ph + 1) * BK, k2 = (2 * ph + 2) * BK;
        loadA(ra1, k1); stageB(1, k1);
        __builtin_amdgcn_sched_barrier(0);
        compute(ra0, 0);
        __syncthreads();
        loadA(ra0, k2); stageB(0, k2);
        __builtin_amdgcn_sched_barrier(0);
        compute(ra1, 1);
        __syncthreads();
    }
    // step 14 (set0/buf0) + prefetch step 15; then step 15 (set1/buf1)
    loadA(ra1, 15 * BK); stageB(1, 15 * BK);
    __builtin_amdgcn_sched_barrier(0);
    compute(ra0, 0);
    __syncthreads();
    compute(ra1, 1);

    // ---- epilogue: D layout row = q*4 + r, col = lane&15; store bf16
    #pragma unroll
    for (int ni = 0; ni < 4; ++ni) {
        const int col = w * 64 + ni * 16 + lm;
        const float bv = bias[col];
        #pragma unroll
        for (int mi = 0; mi < 2; ++mi) {
            const int rbase = m0 + mi * 16 + q * 4;
            #pragma unroll
            for (int r = 0; r < 4; ++r)
                H[(size_t)(rbase + r) * P_DIM + col] = (__bf16)(acc[mi][ni][r] + bv);
        }
    }
}

// ---------------- Kernel 2: span gather (bf16 H -> f32 out) -------------------
// Wave-per-(set,query): lane l covers cols [l*4, l*4+4). 8 pairs per wave,
// fully unrolled -> 16 independent H loads in flight. NT stores for out.
__global__ __launch_bounds__(256) void gather_kernel(const __bf16* __restrict__ H,
                                                     const int* __restrict__ s1,
                                                     const int* __restrict__ e1,
                                                     const int* __restrict__ qb,
                                                     const int* __restrict__ s2,
                                                     const int* __restrict__ e2,
                                                     float* __restrict__ out) {
    const int wave = (blockIdx.x * 256 + threadIdx.x) >> 6;  // 0..2047
    const int l    = threadIdx.x & 63;

    #pragma unroll
    for (int j = 0; j < 8; ++j) {
        const int p   = wave * 8 + j;       // 0..16383
        const int set = p >> 13;
        const int qi  = p & 8191;
        const int s   = set ? s2[qi] : s1[qi];
        const int e   = set ? e2[qi] : e1[qi];
        const int b   = qb[qi];

        f32x4 v0 = {0.f, 0.f, 0.f, 0.f}, v1 = v0;
        if (e >= s) {   // wave-uniform branch
            const bf16x4 a = *(const bf16x4*)(H + ((size_t)b * S_LEN + s) * P_DIM + l * 4);
            const bf16x4 c = *(const bf16x4*)(H + ((size_t)b * S_LEN + e) * P_DIM + l * 4);
            v0[0] = (float)a[0]; v0[1] = (float)a[1]; v0[2] = (float)a[2]; v0[3] = (float)a[3];
            v1[0] = (float)c[0]; v1[1] = (float)c[1]; v1[2] = (float)c[2]; v1[3] = (float)c[3];
        }
        float* op = out + (size_t)set * (NQ_ * 512) + (size_t)qi * 512;
        nts(v0, op + l * 4);
        nts(v1, op + 256 + l * 4);
    }
}

// ---------------- launch ------------------------------------------------------
extern "C" void kernel_launch(void* const* d_in, const int* in_sizes, int n_in,
                              void* d_out, int out_size, void* d_ws, size_t ws_size,
                              hipStream_t stream) {
    const float* A    = (const float*)d_in[1];
    const int*   s1   = (const int*)  d_in[2];
    const int*   e1   = (const int*)  d_in[3];
    const int*   qb   = (const int*)  d_in[4];
    const int*   s2   = (const int*)  d_in[5];
    const int*   e2   = (const int*)  d_in[6];
    const float* W    = (const float*)d_in[7];
    const float* bias = (const float*)d_in[8];
    float*       out  = (float*)d_out;

    __bf16* WT = (__bf16*)d_ws;                        // 512 KB
    __bf16* H  = (__bf16*)((char*)d_ws + (1 << 20));   // 8 MB bf16

    wt_kernel    <<<dim3(32, 8), dim3(32, 32), 0, stream>>>(W, WT);
    gemm_kernel  <<<dim3(M_TOT / BM), dim3(256), 0, stream>>>(A, WT, bias, H);
    gather_kernel<<<dim3(512), dim3(256), 0, stream>>>(H, s1, e1, qb, s2, e2, out);
}

// Round 6
// 152.204 us; speedup vs baseline: 1.0761x; 1.0761x over previous
//
#include <hip/hip_runtime.h>
#include <hip/hip_bf16.h>
#include <stdint.h>

#define S_LEN 2048
#define D_DIM 1024
#define P_DIM 256
#define NQ_   8192
#define M_TOT 16384  // B*S

#define BM 32
#define BN 256
#define BK 32
#define ASTRIDE 40   // A LDS row stride (elements): 80 B -> conflict-free frag reads

typedef __attribute__((ext_vector_type(4))) float  f32x4;
typedef __attribute__((ext_vector_type(8))) __bf16 bf16x8;
typedef __attribute__((ext_vector_type(4))) __bf16 bf16x4;

__device__ __forceinline__ void async16(const void* g, void* l) {
    __builtin_amdgcn_global_load_lds(
        (const __attribute__((address_space(1))) uint32_t*)g,
        (__attribute__((address_space(3))) uint32_t*)l, 16, 0, 0);
}

__device__ __forceinline__ void nts(f32x4 v, float* p) {
    __builtin_nontemporal_store(v, (f32x4*)p);
}

// ---------------- Kernel 0: W [1024][256] f32 -> WT [256][1024] bf16 ----------
__global__ __launch_bounds__(1024) void wt_kernel(const float* __restrict__ W,
                                                  __bf16* __restrict__ WT) {
    __shared__ __bf16 tile[32][33];
    const int k0 = blockIdx.x * 32;
    const int n0 = blockIdx.y * 32;
    const int tx = threadIdx.x, ty = threadIdx.y;
    tile[ty][tx] = (__bf16)W[(k0 + ty) * P_DIM + (n0 + tx)];
    __syncthreads();
    WT[(n0 + ty) * D_DIM + (k0 + tx)] = tile[tx][ty];
}

// ---------------- Kernel 1: H(bf16) = A @ W + b  ------------------------------
// R4 skeleton, re-parametrized BK=32 for 4 blocks/CU (37 KB LDS, 16 waves/CU):
// barrier-drain windows of the 4 co-resident blocks interleave.
// B: async global_load_lds, permutation swizzle s(i,q)=4i+((q+(i>>1))&3)
//    -> frag ds_read_b128 spread over all 8 bank-quads (2-way = free).
// A: coop load to VGPR (128 thr x 32B fp32), cvt, ds_write AFTER compute.
__global__ __launch_bounds__(256, 4) void gemm_kernel(const float*  __restrict__ A,
                                                      const __bf16* __restrict__ WT,
                                                      const float*  __restrict__ bias,
                                                      __bf16*       __restrict__ H) {
    __shared__ __bf16 As[2][BM * ASTRIDE];  // 2.5 KB x2
    __shared__ __bf16 Bs[2][BN * BK];       // 16 KB x2

    const int tid = threadIdx.x;
    const int w   = tid >> 6;
    const int l   = tid & 63;
    const int lm  = l & 15;
    const int q   = l >> 4;

    const int m0 = blockIdx.x * BM;

    // ---- B async staging: wave w, inst j -> region g=w*4+j (16 rows x 32k).
    // Lane l -> slot l: i=l>>2, pos=l&3 holds chunk qf=((l&3)-(l>>3))&3 of
    // row g*16+i  (inverse of s(i,q)=4i+((q+(i>>1))&3)).
    const int bi  = l >> 2;
    const int bqf = ((l & 3) - (l >> 3)) & 3;

    auto stageB = [&](int buf, int k0) {
        #pragma unroll
        for (int j = 0; j < 4; ++j) {
            const int g   = w * 4 + j;
            const int row = g * 16 + bi;
            async16(WT + (size_t)row * D_DIM + k0 + bqf * 8, &Bs[buf][g * 512]);
        }
    };

    // ---- A staging: threads 0..127, r=t>>2, c=t&3: 8 fp32 -> bf16x8.
    const int ar = tid >> 2;
    const int ac = tid & 3;
    const float* agp = A + (size_t)(m0 + ar) * D_DIM + ac * 8;

    float4 fa0, fa1;
    auto loadA = [&](int k0) {
        if (tid < 128) {
            fa0 = *(const float4*)(agp + k0);
            fa1 = *(const float4*)(agp + k0 + 4);
        }
    };
    auto writeA = [&](int buf) {
        if (tid < 128) {
            bf16x8 v;
            v[0] = (__bf16)fa0.x; v[1] = (__bf16)fa0.y; v[2] = (__bf16)fa0.z; v[3] = (__bf16)fa0.w;
            v[4] = (__bf16)fa1.x; v[5] = (__bf16)fa1.y; v[6] = (__bf16)fa1.z; v[7] = (__bf16)fa1.w;
            *(bf16x8*)(&As[buf][ar * ASTRIDE + ac * 8]) = v;
        }
    };

    f32x4 acc[2][4] = {};

    auto compute = [&](int buf) {
        bf16x8 af[2], bfr[4];
        #pragma unroll
        for (int mi = 0; mi < 2; ++mi)
            af[mi] = *(const bf16x8*)(&As[buf][(mi * 16 + lm) * ASTRIDE + q * 8]);
        #pragma unroll
        for (int ni = 0; ni < 4; ++ni) {
            const int g = w * 4 + ni;
            bfr[ni] = *(const bf16x8*)(&Bs[buf][g * 512 + lm * 32 + ((q + (lm >> 1)) & 3) * 8]);
        }
        #pragma unroll
        for (int mi = 0; mi < 2; ++mi)
            #pragma unroll
            for (int ni = 0; ni < 4; ++ni)
                acc[mi][ni] = __builtin_amdgcn_mfma_f32_16x16x32_bf16(
                    af[mi], bfr[ni], acc[mi][ni], 0, 0, 0);
    };

    // ---- pipeline: 32 K-steps, step s -> buf s&1.
    loadA(0);
    stageB(0, 0);
    writeA(0);
    __syncthreads();

    #pragma unroll 1
    for (int ph = 0; ph < 15; ++ph) {
        const int k1 = (2 * ph + 1) * BK, k2 = (2 * ph + 2) * BK;
        loadA(k1); stageB(1, k1);
        __builtin_amdgcn_sched_barrier(0);
        compute(0);
        __builtin_amdgcn_sched_barrier(0);
        writeA(1);
        __syncthreads();
        loadA(k2); stageB(0, k2);
        __builtin_amdgcn_sched_barrier(0);
        compute(1);
        __builtin_amdgcn_sched_barrier(0);
        writeA(0);
        __syncthreads();
    }
    // tail: stage step 31 (buf1), compute step 30 (buf0), then step 31
    loadA(31 * BK); stageB(1, 31 * BK);
    __builtin_amdgcn_sched_barrier(0);
    compute(0);
    __builtin_amdgcn_sched_barrier(0);
    writeA(1);
    __syncthreads();
    compute(1);

    // ---- epilogue: D layout row = q*4 + r, col = lane&15; bf16 store
    #pragma unroll
    for (int ni = 0; ni < 4; ++ni) {
        const int col = w * 64 + ni * 16 + lm;
        const float bv = bias[col];
        #pragma unroll
        for (int mi = 0; mi < 2; ++mi) {
            const int rbase = m0 + mi * 16 + q * 4;
            #pragma unroll
            for (int r = 0; r < 4; ++r)
                H[(size_t)(rbase + r) * P_DIM + col] = (__bf16)(acc[mi][ni][r] + bv);
        }
    }
}

// ---------------- Kernel 2: span gather (bf16 H -> f32 out) -------------------
__global__ __launch_bounds__(256) void gather_kernel(const __bf16* __restrict__ H,
                                                     const int* __restrict__ s1,
                                                     const int* __restrict__ e1,
                                                     const int* __restrict__ qb,
                                                     const int* __restrict__ s2,
                                                     const int* __restrict__ e2,
                                                     float* __restrict__ out) {
    const int wave = (blockIdx.x * 256 + threadIdx.x) >> 6;  // 0..2047
    const int l    = threadIdx.x & 63;

    #pragma unroll
    for (int j = 0; j < 8; ++j) {
        const int p   = wave * 8 + j;       // 0..16383
        const int set = p >> 13;
        const int qi  = p & 8191;
        const int s   = set ? s2[qi] : s1[qi];
        const int e   = set ? e2[qi] : e1[qi];
        const int b   = qb[qi];

        f32x4 v0 = {0.f, 0.f, 0.f, 0.f}, v1 = v0;
        if (e >= s) {   // wave-uniform branch
            const bf16x4 a = *(const bf16x4*)(H + ((size_t)b * S_LEN + s) * P_DIM + l * 4);
            const bf16x4 c = *(const bf16x4*)(H + ((size_t)b * S_LEN + e) * P_DIM + l * 4);
            v0[0] = (float)a[0]; v0[1] = (float)a[1]; v0[2] = (float)a[2]; v0[3] = (float)a[3];
            v1[0] = (float)c[0]; v1[1] = (float)c[1]; v1[2] = (float)c[2]; v1[3] = (float)c[3];
        }
        float* op = out + (size_t)set * (NQ_ * 512) + (size_t)qi * 512;
        nts(v0, op + l * 4);
        nts(v1, op + 256 + l * 4);
    }
}

// ---------------- launch ------------------------------------------------------
extern "C" void kernel_launch(void* const* d_in, const int* in_sizes, int n_in,
                              void* d_out, int out_size, void* d_ws, size_t ws_size,
                              hipStream_t stream) {
    const float* A    = (const float*)d_in[1];
    const int*   s1   = (const int*)  d_in[2];
    const int*   e1   = (const int*)  d_in[3];
    const int*   qb   = (const int*)  d_in[4];
    const int*   s2   = (const int*)  d_in[5];
    const int*   e2   = (const int*)  d_in[6];
    const float* W    = (const float*)d_in[7];
    const float* bias = (const float*)d_in[8];
    float*       out  = (float*)d_out;

    __bf16* WT = (__bf16*)d_ws;                        // 512 KB
    __bf16* H  = (__bf16*)((char*)d_ws + (1 << 20));   // 8 MB bf16

    wt_kernel    <<<dim3(32, 8), dim3(32, 32), 0, stream>>>(W, WT);
    gemm_kernel  <<<dim3(M_TOT / BM), dim3(256), 0, stream>>>(A, WT, bias, H);
    gather_kernel<<<dim3(512), dim3(256), 0, stream>>>(H, s1, e1, qb, s2, e2, out);
}

// Round 7
// 149.949 us; speedup vs baseline: 1.0923x; 1.0150x over previous
//
#include <hip/hip_runtime.h>
#include <hip/hip_bf16.h>
#include <stdint.h>

#define S_LEN 2048
#define D_DIM 1024
#define P_DIM 256
#define NQ_   8192
#define M_TOT 16384  // B*S

#define BM 32
#define BN 256
#define BK 64

typedef __attribute__((ext_vector_type(4))) float  f32x4;
typedef __attribute__((ext_vector_type(8))) __bf16 bf16x8;
typedef __attribute__((ext_vector_type(4))) __bf16 bf16x4;

__device__ __forceinline__ void async16(const void* g, void* l) {
    __builtin_amdgcn_global_load_lds(
        (const __attribute__((address_space(1))) uint32_t*)g,
        (__attribute__((address_space(3))) uint32_t*)l, 16, 0, 0);
}

__device__ __forceinline__ void nts(f32x4 v, float* p) {
    __builtin_nontemporal_store(v, (f32x4*)p);
}

// ---------------- Kernel 0: W [1024][256] f32 -> WT [256][1024] bf16 ----------
__global__ __launch_bounds__(1024) void wt_kernel(const float* __restrict__ W,
                                                  __bf16* __restrict__ WT) {
    __shared__ __bf16 tile[32][33];
    const int k0 = blockIdx.x * 32;
    const int n0 = blockIdx.y * 32;
    const int tx = threadIdx.x, ty = threadIdx.y;
    tile[ty][tx] = (__bf16)W[(k0 + ty) * P_DIM + (n0 + tx)];
    __syncthreads();
    WT[(n0 + ty) * D_DIM + (k0 + tx)] = tile[tx][ty];
}

// ---------------- Kernel 1: H(bf16) = A @ W + b  ------------------------------
// Key restructure (R7): B NEVER enters the vmcnt queue at barrier time.
//  - B frags: global->VGPR each step (WT is 512 KB, L2-resident), issued right
//    after the barrier, consumed by MFMAs via compiler's fine-grained vmcnt(N).
//  - A: async global_load_lds fp32 double-buffer (8 KB/step); stage for k+1
//    issued AFTER this step's B loads (vmcnt is in-order: B waits then don't
//    drain A), giving A a full step to land before the vmcnt(0) barrier.
//  - A chunks XOR-16 swizzled on the GLOBAL side (lane-contiguity preserved);
//    frag ds_read_b128s then hit banks 2-way = free. fp32->bf16 cvt in compute.
// BM=32,BN=256,BK=64; 256 thr/4 waves; grid=512 -> 2 blocks/CU. LDS 16 KB.
__global__ __launch_bounds__(256, 2) void gemm_kernel(const float*  __restrict__ A,
                                                      const __bf16* __restrict__ WT,
                                                      const float*  __restrict__ bias,
                                                      __bf16*       __restrict__ H) {
    __shared__ float As[2][BM * BK];   // 8 KB x2, fp32, XOR-swizzled 16B chunks

    const int tid = threadIdx.x;
    const int w   = tid >> 6;
    const int l   = tid & 63;
    const int lm  = l & 15;
    const int q   = l >> 4;

    const int m0 = blockIdx.x * BM;

    // ---- A async staging: wave w issues insts j=2w,2w+1; inst j covers rows
    // 4j..4j+3 (1 KB). Lane l -> row 4j+(l>>4), dest chunk l&15 holds k-chunk
    // c = (l&15) ^ (row & 15)  (16B fp32 chunks, XOR-16 swizzle).
    auto stageA = [&](int buf, int k0) {
        #pragma unroll
        for (int jj = 0; jj < 2; ++jj) {
            const int j = 2 * w + jj;
            const int r = 4 * j + (l >> 4);
            const int c = (l & 15) ^ (r & 15);
            async16(A + (size_t)(m0 + r) * D_DIM + k0 + c * 4,
                    &As[buf][j * 256]);          // wave-uniform base; HW adds lane*16
        }
    };

    f32x4 acc[2][4] = {};

    const __bf16* wp = WT + (size_t)(w * 64 + lm) * D_DIM + q * 8;

    auto step = [&](int buf, int k0, int kstage) {
        // ---- B frags: 8x global_load_dwordx4 from L2 (issued FIRST)
        bf16x8 rb[2][4];
        #pragma unroll
        for (int kh = 0; kh < 2; ++kh)
            #pragma unroll
            for (int ni = 0; ni < 4; ++ni)
                rb[kh][ni] = *(const bf16x8*)(wp + (size_t)ni * 16 * D_DIM + k0 + kh * 32);
        // ---- A stage for next step (after B: B's vmcnt waits leave A in flight)
        if (kstage >= 0) stageA(buf ^ 1, kstage);
        __builtin_amdgcn_sched_barrier(0);
        // ---- compute: ds_read A (swizzled), cvt->bf16, 16 MFMAs
        #pragma unroll
        for (int kh = 0; kh < 2; ++kh) {
            bf16x8 af[2];
            #pragma unroll
            for (int mi = 0; mi < 2; ++mi) {
                const int row = mi * 16 + lm;
                const int c0  = kh * 8 + q * 2;
                const f32x4 a0 = *(const f32x4*)(&As[buf][row * BK + ((c0 ^ lm) * 4)]);
                const f32x4 a1 = *(const f32x4*)(&As[buf][row * BK + (((c0 + 1) ^ lm) * 4)]);
                af[mi][0] = (__bf16)a0[0]; af[mi][1] = (__bf16)a0[1];
                af[mi][2] = (__bf16)a0[2]; af[mi][3] = (__bf16)a0[3];
                af[mi][4] = (__bf16)a1[0]; af[mi][5] = (__bf16)a1[1];
                af[mi][6] = (__bf16)a1[2]; af[mi][7] = (__bf16)a1[3];
            }
            #pragma unroll
            for (int mi = 0; mi < 2; ++mi)
                #pragma unroll
                for (int ni = 0; ni < 4; ++ni)
                    acc[mi][ni] = __builtin_amdgcn_mfma_f32_16x16x32_bf16(
                        af[mi], rb[kh][ni], acc[mi][ni], 0, 0, 0);
        }
        __syncthreads();   // drains only the 2 stageA insts (issued ~a step ago)
    };

    stageA(0, 0);
    __syncthreads();

    #pragma unroll 1
    for (int ph = 0; ph < 7; ++ph) {
        step(0, (2 * ph) * BK,     (2 * ph + 1) * BK);
        step(1, (2 * ph + 1) * BK, (2 * ph + 2) * BK);
    }
    step(0, 14 * BK, 15 * BK);
    step(1, 15 * BK, -1);

    // ---- epilogue: D layout row = q*4 + r, col = lane&15; bf16 store
    #pragma unroll
    for (int ni = 0; ni < 4; ++ni) {
        const int col = w * 64 + ni * 16 + lm;
        const float bv = bias[col];
        #pragma unroll
        for (int mi = 0; mi < 2; ++mi) {
            const int rbase = m0 + mi * 16 + q * 4;
            #pragma unroll
            for (int r = 0; r < 4; ++r)
                H[(size_t)(rbase + r) * P_DIM + col] = (__bf16)(acc[mi][ni][r] + bv);
        }
    }
}

// ---------------- Kernel 2: span gather (bf16 H -> f32 out) -------------------
__global__ __launch_bounds__(256) void gather_kernel(const __bf16* __restrict__ H,
                                                     const int* __restrict__ s1,
                                                     const int* __restrict__ e1,
                                                     const int* __restrict__ qb,
                                                     const int* __restrict__ s2,
                                                     const int* __restrict__ e2,
                                                     float* __restrict__ out) {
    const int wave = (blockIdx.x * 256 + threadIdx.x) >> 6;  // 0..2047
    const int l    = threadIdx.x & 63;

    #pragma unroll
    for (int j = 0; j < 8; ++j) {
        const int p   = wave * 8 + j;       // 0..16383
        const int set = p >> 13;
        const int qi  = p & 8191;
        const int s   = set ? s2[qi] : s1[qi];
        const int e   = set ? e2[qi] : e1[qi];
        const int b   = qb[qi];

        f32x4 v0 = {0.f, 0.f, 0.f, 0.f}, v1 = v0;
        if (e >= s) {   // wave-uniform branch
            const bf16x4 a = *(const bf16x4*)(H + ((size_t)b * S_LEN + s) * P_DIM + l * 4);
            const bf16x4 c = *(const bf16x4*)(H + ((size_t)b * S_LEN + e) * P_DIM + l * 4);
            v0[0] = (float)a[0]; v0[1] = (float)a[1]; v0[2] = (float)a[2]; v0[3] = (float)a[3];
            v1[0] = (float)c[0]; v1[1] = (float)c[1]; v1[2] = (float)c[2]; v1[3] = (float)c[3];
        }
        float* op = out + (size_t)set * (NQ_ * 512) + (size_t)qi * 512;
        nts(v0, op + l * 4);
        nts(v1, op + 256 + l * 4);
    }
}

// ---------------- launch ------------------------------------------------------
extern "C" void kernel_launch(void* const* d_in, const int* in_sizes, int n_in,
                              void* d_out, int out_size, void* d_ws, size_t ws_size,
                              hipStream_t stream) {
    const float* A    = (const float*)d_in[1];
    const int*   s1   = (const int*)  d_in[2];
    const int*   e1   = (const int*)  d_in[3];
    const int*   qb   = (const int*)  d_in[4];
    const int*   s2   = (const int*)  d_in[5];
    const int*   e2   = (const int*)  d_in[6];
    const float* W    = (const float*)d_in[7];
    const float* bias = (const float*)d_in[8];
    float*       out  = (float*)d_out;

    __bf16* WT = (__bf16*)d_ws;                        // 512 KB
    __bf16* H  = (__bf16*)((char*)d_ws + (1 << 20));   // 8 MB bf16

    wt_kernel    <<<dim3(32, 8), dim3(32, 32), 0, stream>>>(W, WT);
    gemm_kernel  <<<dim3(M_TOT / BM), dim3(256), 0, stream>>>(A, WT, bias, H);
    gather_kernel<<<dim3(512), dim3(256), 0, stream>>>(H, s1, e1, qb, s2, e2, out);
}